// Round 3
// baseline (227.020 us; speedup 1.0000x reference)
//
#include <hip/hip_runtime.h>
#include <hip/hip_bf16.h>

// VariableSelectionNetwork (TFT VSN) fused kernel for MI355X / gfx950.
// B=64 T=512 F=32 U=64, rows N = B*T = 32768.
// out = concat( out[N][64], w[N][32] ) in f32.
//
// R2: RPB=64 / 256 thr / 512 blocks -> 2 independent blocks per CU
//     (LDS 77312 B, x2 = 150.6KB <= 160KB). bf16 h2 roundtrip, bf16 wtl,
//     native bf16 converts. Double-buffered weights (1 barrier per f).

typedef float f4      __attribute__((ext_vector_type(4)));
typedef float f32x4   __attribute__((ext_vector_type(4)));
typedef short bf16x8  __attribute__((ext_vector_type(8)));
typedef unsigned short u16x8 __attribute__((ext_vector_type(8)));

#define N_ROWS 32768
#define F_DIM  32
#define U_DIM  64
#define RPB    64           // rows per block
#define NTHR   256          // 4 waves
#define NBLK   (N_ROWS / RPB)   // 512

// ---- LDS byte offsets (total 77312 B) ----
#define X_OFF   0           // float  [64][36]        x tile (padded)
#define WT_OFF  9216        // ushort [64][40]        softmax weights tile (bf16)
#define WB_OFF  14336       // ushort [2][3][64*64]   bf16 W2/Wg1/Wg2 (dbuf, swizzled)
#define VB_OFF  63488       // float  [2][9][64]      per-f vectors (dbuf)
#define H2_OFF  68096       // ushort [4][16][72]     per-wave h2 scratch (bf16)
#define SMEM_BYTES 77312

__device__ __forceinline__ unsigned short bfu(float x) {
  union { __hip_bfloat16 h; unsigned short u; } c;
  c.h = __float2bfloat16(x);
  return c.u;
}
__device__ __forceinline__ float bf2f(unsigned short u) {
  union { float f; unsigned v; } c; c.v = ((unsigned)u) << 16; return c.f;
}

// =====================================================================
// prep: transpose W2/Wg1/Wg2 -> bf16 [m][f][v][u] in ws; pack 9 vec tables
// =====================================================================
__global__ __launch_bounds__(256) void vsn_prep(
    const float* __restrict__ W2,  const float* __restrict__ Wg1, const float* __restrict__ Wg2,
    const float* __restrict__ W1,  const float* __restrict__ b1,  const float* __restrict__ b2,
    const float* __restrict__ bg1, const float* __restrict__ bg2,
    const float* __restrict__ Wp,  const float* __restrict__ bp,
    const float* __restrict__ gamma_, const float* __restrict__ beta_,
    unsigned short* __restrict__ wtg, float* __restrict__ vect)
{
  const int t = threadIdx.x, blk = blockIdx.x;
  if (blk < 96) {
    __shared__ float tile[64][65];
    const int m = blk >> 5, f = blk & 31;
    const float* src = (m == 0) ? W2 : (m == 1) ? Wg1 : Wg2;
    src += f * 4096;
    #pragma unroll
    for (int i = 0; i < 16; ++i) {
      int idx = t + i * 256;
      tile[idx >> 6][idx & 63] = src[idx];
    }
    __syncthreads();
    unsigned short* dst = wtg + (m * 32 + f) * 4096;
    #pragma unroll
    for (int i = 0; i < 16; ++i) {
      int idx = t + i * 256;                       // idx = v*64 + u
      dst[idx] = bfu(tile[idx & 63][idx >> 6]);    // = W[f][u][v]
    }
  } else {
    // vec table: [f][a][64], a: 0 W1,1 b1,2 b2,3 bg1,4 bg2,5 Wp,6 bp,7 gamma,8 beta
    #pragma unroll
    for (int a = 0; a < 9; ++a) {
      const float* s = (a==0)?W1:(a==1)?b1:(a==2)?b2:(a==3)?bg1:(a==4)?bg2:
                       (a==5)?Wp:(a==6)?bp:(a==7)?gamma_:beta_;
      for (int i = t; i < 2048; i += 256)
        vect[(i >> 6) * 576 + a * 64 + (i & 63)] = s[i];
    }
  }
}

// =====================================================================
// main fused kernel
// =====================================================================
__global__ __launch_bounds__(NTHR, 2) void vsn_main(
    const float* __restrict__ x,
    const unsigned short* __restrict__ wtg,   // [3][32][64][64] bf16, [v][u]
    const float* __restrict__ vect,           // [32][9][64]
    const float* __restrict__ w1w, const float* __restrict__ w2w,
    const float* __restrict__ wg1w, const float* __restrict__ wg2w,
    const float* __restrict__ b1w, const float* __restrict__ b2w,
    const float* __restrict__ bg1w, const float* __restrict__ bg2w,
    const float* __restrict__ gammaw, const float* __restrict__ betaw,
    float* __restrict__ out, float* __restrict__ wout)
{
  __shared__ __align__(16) char smem[SMEM_BYTES];
  const int t  = threadIdx.x;
  const int r0 = blockIdx.x * RPB;

  float* xt  = (float*)(smem + X_OFF);               // [64][36] f32
  unsigned short* wtlb = (unsigned short*)(smem + WT_OFF);  // [64][40] bf16
  unsigned short* wbuf = (unsigned short*)(smem + WB_OFF);
  float* vbuf = (float*)(smem + VB_OFF);
  unsigned short* h2b = (unsigned short*)(smem + H2_OFF);   // [4][16][72] bf16
  // phase-A overlays
  float* wAl = (float*)(smem + WB_OFF);              // [4][32][32] f32
  float* vAl = (float*)(smem + WB_OFF + 16384);      // [6][32] f32
  float* hex = (float*)(smem + H2_OFF);              // [64][36] f32

  // ---- stage x tile (coalesced f32x4) ----
  #pragma unroll
  for (int i = 0; i < 2; ++i) {
    int i4 = t + i * NTHR;                   // 0..511
    f4 v = ((const f4*)(x + (size_t)r0 * F_DIM))[i4];
    *((f4*)(xt + (i4 >> 3) * 36 + ((i4 & 7) << 2))) = v;
  }

  // ---- prefetch f=0 phase-B weights into regs (held through phase A) ----
  int4 pw0[2], pw1[2], pw2[2]; f4 pv0;
  {
    const int4* wt4 = (const int4*)wtg;      // 512 int4 per (m,f)
    #pragma unroll
    for (int j = 0; j < 2; ++j) {
      pw0[j] = wt4[(0 * 32 + 0) * 512 + t + j * 256];
      pw1[j] = wt4[(1 * 32 + 0) * 512 + t + j * 256];
      pw2[j] = wt4[(2 * 32 + 0) * 512 + t + j * 256];
    }
    if (t < 144) pv0 = ((const f4*)(vect))[t];
  }

  // ---- stage phase-A weights ----
  #pragma unroll
  for (int i = 0; i < 4; ++i) {
    int i4 = t + i * NTHR;                   // 0..1023
    int m = i4 >> 8, off = (i4 & 255) << 2;
    const float* src = (m == 0) ? w1w : (m == 1) ? w2w : (m == 2) ? wg1w : wg2w;
    *(f4*)(wAl + m * 1024 + off) = *((const f4*)(src + off));
  }
  if (t < 48) {
    int m = t >> 3, off = (t & 7) << 2;
    const float* src = (m==0)?b1w:(m==1)?b2w:(m==2)?bg1w:(m==3)?bg2w:(m==4)?gammaw:betaw;
    *(f4*)(vAl + m * 32 + off) = *((const f4*)(src + off));
  }
  __syncthreads();

  // ================= PHASE A : weights GRN + softmax =================
  {
    const int ar = t >> 2;        // row 0..63
    const int g0 = (t & 3) << 3;  // this thread's 8 output columns

    // stage 1: h1 = elu(x @ w1w + b1w)
    float hacc[8];
    #pragma unroll
    for (int j = 0; j < 8; ++j) hacc[j] = vAl[0 * 32 + g0 + j];
    #pragma unroll
    for (int ff = 0; ff < 32; ++ff) {
      float xv = xt[ar * 36 + ff];
      f4 w0 = *(const f4*)(wAl + 0 * 1024 + ff * 32 + g0);
      f4 w1 = *(const f4*)(wAl + 0 * 1024 + ff * 32 + g0 + 4);
      #pragma unroll
      for (int j = 0; j < 4; ++j) { hacc[j] += xv * w0[j]; hacc[4 + j] += xv * w1[j]; }
    }
    #pragma unroll
    for (int j = 0; j < 8; ++j) { float z = hacc[j]; hacc[j] = z > 0.f ? z : (__expf(z) - 1.f); }
    *(f4*)(hex + ar * 36 + g0)     = (f4){hacc[0], hacc[1], hacc[2], hacc[3]};
    *(f4*)(hex + ar * 36 + g0 + 4) = (f4){hacc[4], hacc[5], hacc[6], hacc[7]};
    __syncthreads();

    // stage 2: h2 = h1 @ w2w + b2w
    float h2acc[8];
    #pragma unroll
    for (int j = 0; j < 8; ++j) h2acc[j] = vAl[1 * 32 + g0 + j];
    #pragma unroll
    for (int ff = 0; ff < 32; ++ff) {
      float hv = hex[ar * 36 + ff];
      f4 w0 = *(const f4*)(wAl + 1 * 1024 + ff * 32 + g0);
      f4 w1 = *(const f4*)(wAl + 1 * 1024 + ff * 32 + g0 + 4);
      #pragma unroll
      for (int j = 0; j < 4; ++j) { h2acc[j] += hv * w0[j]; h2acc[4 + j] += hv * w1[j]; }
    }
    __syncthreads();   // everyone done reading h1 from hex
    *(f4*)(hex + ar * 36 + g0)     = (f4){h2acc[0], h2acc[1], h2acc[2], h2acc[3]};
    *(f4*)(hex + ar * 36 + g0 + 4) = (f4){h2acc[4], h2acc[5], h2acc[6], h2acc[7]};
    __syncthreads();

    // stage 3: GLU
    float aacc[8], bacc[8];
    #pragma unroll
    for (int j = 0; j < 8; ++j) { aacc[j] = vAl[2 * 32 + g0 + j]; bacc[j] = vAl[3 * 32 + g0 + j]; }
    #pragma unroll
    for (int ff = 0; ff < 32; ++ff) {
      float hv = hex[ar * 36 + ff];
      f4 wa0 = *(const f4*)(wAl + 2 * 1024 + ff * 32 + g0);
      f4 wa1 = *(const f4*)(wAl + 2 * 1024 + ff * 32 + g0 + 4);
      f4 wb0 = *(const f4*)(wAl + 3 * 1024 + ff * 32 + g0);
      f4 wb1 = *(const f4*)(wAl + 3 * 1024 + ff * 32 + g0 + 4);
      #pragma unroll
      for (int j = 0; j < 4; ++j) {
        aacc[j] += hv * wa0[j]; aacc[4 + j] += hv * wa1[j];
        bacc[j] += hv * wb0[j]; bacc[4 + j] += hv * wb1[j];
      }
    }
    float zz[8];
    #pragma unroll
    for (int j = 0; j < 8; ++j) {
      float sg = __builtin_amdgcn_rcpf(1.f + __expf(-bacc[j]));
      zz[j] = aacc[j] * sg + xt[ar * 36 + g0 + j];    // GLU + residual
    }
    __syncthreads();   // done reading h2 from hex
    *(f4*)(hex + ar * 36 + g0)     = (f4){zz[0], zz[1], zz[2], zz[3]};
    *(f4*)(hex + ar * 36 + g0 + 4) = (f4){zz[4], zz[5], zz[6], zz[7]};
    __syncthreads();

    // LN + softmax over F=32 (each thread redundantly reduces its row from LDS)
    float s1 = 0.f, s2 = 0.f;
    #pragma unroll
    for (int ff = 0; ff < 32; ++ff) { float z = hex[ar * 36 + ff]; s1 += z; s2 += z * z; }
    float mA = s1 * 0.03125f;
    float vA = s2 * 0.03125f - mA * mA;
    float rsA = __builtin_amdgcn_rsqf(vA + 1e-3f);
    float mx = -1e30f;
    #pragma unroll
    for (int ff = 0; ff < 32; ++ff) {
      float y = (hex[ar * 36 + ff] - mA) * rsA * vAl[4 * 32 + ff] + vAl[5 * 32 + ff];
      mx = fmaxf(mx, y);
    }
    float es = 0.f;
    #pragma unroll
    for (int ff = 0; ff < 32; ++ff) {
      float y = (hex[ar * 36 + ff] - mA) * rsA * vAl[4 * 32 + ff] + vAl[5 * 32 + ff];
      es += __expf(y - mx);
    }
    float inv = __builtin_amdgcn_rcpf(es);
    float wv8[8];
    u16x8 wu;
    #pragma unroll
    for (int j = 0; j < 8; ++j) {
      float y = (hex[ar * 36 + g0 + j] - mA) * rsA * vAl[4 * 32 + g0 + j] + vAl[5 * 32 + g0 + j];
      wv8[j] = __expf(y - mx) * inv;
      wu[j] = bfu(wv8[j]);
    }
    *(u16x8*)(wtlb + ar * 40 + g0) = wu;   // bf16 copy for phase B
    *(f4*)(wout + (size_t)(r0 + ar) * 32 + g0)     = (f4){wv8[0], wv8[1], wv8[2], wv8[3]};
    *(f4*)(wout + (size_t)(r0 + ar) * 32 + g0 + 4) = (f4){wv8[4], wv8[5], wv8[6], wv8[7]};
    __syncthreads();   // phase A done; wAl/hex regions are now free
  }

  // ---- write f=0 phase-B weights (swizzled) into buffer 0 ----
  {
    #pragma unroll
    for (int j = 0; j < 2; ++j) {
      const int p = t + j * 256;
      const int sw = (p * 16) ^ (((p >> 3) & 7) << 4);
      char* wb0 = (char*)wbuf;
      *(int4*)(wb0 + 0 * 8192 + sw) = pw0[j];
      *(int4*)(wb0 + 1 * 8192 + sw) = pw1[j];
      *(int4*)(wb0 + 2 * 8192 + sw) = pw2[j];
    }
    if (t < 144) *(f4*)(vbuf + t * 4) = pv0;
  }
  __syncthreads();

  // ================= PHASE B : per-feature GRNs (MFMA) =================
  const int wid = t >> 6;          // wave 0..3  (16 rows each)
  const int lr  = t & 15;          // A-row / B-col base
  const int lg  = (t >> 4) & 3;    // quarter-group
  unsigned short* h2w = h2b + wid * (16 * 72);   // wave-private [16][72] bf16

  f32x4 acc[4];
  #pragma unroll
  for (int nt = 0; nt < 4; ++nt) acc[nt] = (f32x4){0.f, 0.f, 0.f, 0.f};

  int cur = 0;
  for (int f = 0; f < F_DIM; ++f) {
    // prefetch f+1 weights into regs
    int4 qw0[2], qw1[2], qw2[2]; f4 qv;
    if (f < 31) {
      const int4* wt4 = (const int4*)wtg;
      #pragma unroll
      for (int j = 0; j < 2; ++j) {
        qw0[j] = wt4[(0 * 32 + f + 1) * 512 + t + j * 256];
        qw1[j] = wt4[(1 * 32 + f + 1) * 512 + t + j * 256];
        qw2[j] = wt4[(2 * 32 + f + 1) * 512 + t + j * 256];
      }
      if (t < 144) qv = ((const f4*)(vect + (f + 1) * 576))[t];
    }

    const char*  wbc = (const char*)wbuf + cur * 24576;
    const float* vbc = vbuf + cur * 576;

    // ---- h1 A-fragments, built in registers (rank-1 + ELU) ----
    const float s_ = xt[(wid * 16 + lr) * 36 + f];
    bf16x8 afr[2];
    #pragma unroll
    for (int kt = 0; kt < 2; ++kt) {
      const int u0 = 8 * lg + 32 * kt;
      f4 wa  = *(const f4*)(vbc + u0);
      f4 wb_ = *(const f4*)(vbc + u0 + 4);
      f4 ba  = *(const f4*)(vbc + 64 + u0);
      f4 bb_ = *(const f4*)(vbc + 64 + u0 + 4);
      bf16x8 af;
      #pragma unroll
      for (int j = 0; j < 4; ++j) {
        float h = s_ * wa[j] + ba[j];
        h = h > 0.f ? h : (__expf(h) - 1.f);
        af[j] = (short)bfu(h);
      }
      #pragma unroll
      for (int j = 0; j < 4; ++j) {
        float h = s_ * wb_[j] + bb_[j];
        h = h > 0.f ? h : (__expf(h) - 1.f);
        af[4 + j] = (short)bfu(h);
      }
      afr[kt] = af;
    }

    // ---- GEMM1: h2 = h1 @ W2 ----
    f32x4 c1[4];
    #pragma unroll
    for (int nt = 0; nt < 4; ++nt) {
      c1[nt] = (f32x4){0.f, 0.f, 0.f, 0.f};
      const int v_ = lr + 16 * nt;
      #pragma unroll
      for (int kt = 0; kt < 2; ++kt) {
        int bo = (v_ << 7) + ((8 * lg + 32 * kt) << 1);
        bo ^= (v_ & 7) << 4;
        bf16x8 bfr = *(const bf16x8*)(wbc + 0 * 8192 + bo);
        c1[nt] = __builtin_amdgcn_mfma_f32_16x16x32_bf16(afr[kt], bfr, c1[nt], 0, 0, 0);
      }
    }

    // ---- h2 (+b2) -> wave-private LDS as bf16 ----
    #pragma unroll
    for (int nt = 0; nt < 4; ++nt) {
      const float b2v = vbc[2 * 64 + lr + 16 * nt];
      #pragma unroll
      for (int rg = 0; rg < 4; ++rg)
        h2w[(4 * lg + rg) * 72 + lr + 16 * nt] = bfu(c1[nt][rg] + b2v);
    }
    asm volatile("s_waitcnt lgkmcnt(0)" ::: "memory");

    // ---- A2 fragments read directly as bf16 ----
    bf16x8 a2[2];
    #pragma unroll
    for (int kt = 0; kt < 2; ++kt)
      a2[kt] = *(const bf16x8*)(h2w + lr * 72 + 8 * lg + 32 * kt);

    // ---- GEMM2a / GEMM2b ----
    f32x4 ca[4], cb[4];
    #pragma unroll
    for (int nt = 0; nt < 4; ++nt) { ca[nt] = (f32x4){0.f,0.f,0.f,0.f}; cb[nt] = (f32x4){0.f,0.f,0.f,0.f}; }
    #pragma unroll
    for (int nt = 0; nt < 4; ++nt) {
      const int v_ = lr + 16 * nt;
      #pragma unroll
      for (int kt = 0; kt < 2; ++kt) {
        int bo = (v_ << 7) + ((8 * lg + 32 * kt) << 1);
        bo ^= (v_ & 7) << 4;
        bf16x8 b1f = *(const bf16x8*)(wbc + 1 * 8192 + bo);
        bf16x8 b2f = *(const bf16x8*)(wbc + 2 * 8192 + bo);
        ca[nt] = __builtin_amdgcn_mfma_f32_16x16x32_bf16(a2[kt], b1f, ca[nt], 0, 0, 0);
        cb[nt] = __builtin_amdgcn_mfma_f32_16x16x32_bf16(a2[kt], b2f, cb[nt], 0, 0, 0);
      }
    }

    // ---- epilogue: GLU + residual + LN + weighted accumulate ----
    float xr[4], wr[4];
    #pragma unroll
    for (int rg = 0; rg < 4; ++rg) {
      const int rl = wid * 16 + 4 * lg + rg;
      xr[rg] = xt[rl * 36 + f];
      wr[rg] = bf2f(wtlb[rl * 40 + f]);
    }
    float zf[4][4];
    float s1[4] = {0.f,0.f,0.f,0.f}, s2[4] = {0.f,0.f,0.f,0.f};
    #pragma unroll
    for (int nt = 0; nt < 4; ++nt) {
      const int u = lr + 16 * nt;
      const float bg1v = vbc[3 * 64 + u], bg2v = vbc[4 * 64 + u];
      const float wpv  = vbc[5 * 64 + u], bpv  = vbc[6 * 64 + u];
      #pragma unroll
      for (int rg = 0; rg < 4; ++rg) {
        float a = ca[nt][rg] + bg1v;
        float b = cb[nt][rg] + bg2v;
        float sg = __builtin_amdgcn_rcpf(1.f + __expf(-b));
        float z = a * sg + (xr[rg] * wpv + bpv);
        zf[nt][rg] = z;
        s1[rg] += z;
        s2[rg] += z * z;
      }
    }
    #pragma unroll
    for (int rg = 0; rg < 4; ++rg) {
      #pragma unroll
      for (int m = 1; m < 16; m <<= 1) {
        s1[rg] += __shfl_xor(s1[rg], m, 64);
        s2[rg] += __shfl_xor(s2[rg], m, 64);
      }
    }
    float mn[4], rs[4];
    #pragma unroll
    for (int rg = 0; rg < 4; ++rg) {
      mn[rg] = s1[rg] * 0.015625f;
      float var = s2[rg] * 0.015625f - mn[rg] * mn[rg];
      rs[rg] = __builtin_amdgcn_rsqf(var + 1e-3f);
    }
    #pragma unroll
    for (int nt = 0; nt < 4; ++nt) {
      const int u = lr + 16 * nt;
      const float gav = vbc[7 * 64 + u], bev = vbc[8 * 64 + u];
      #pragma unroll
      for (int rg = 0; rg < 4; ++rg) {
        float y = (zf[nt][rg] - mn[rg]) * rs[rg] * gav + bev;
        acc[nt][rg] += y * wr[rg];
      }
    }

    // ---- stage f+1 weights into the other buffer ----
    if (f < 31) {
      char* wbn = (char*)wbuf + (cur ^ 1) * 24576;
      #pragma unroll
      for (int j = 0; j < 2; ++j) {
        const int p = t + j * 256;
        const int sw = (p * 16) ^ (((p >> 3) & 7) << 4);
        *(int4*)(wbn + 0 * 8192 + sw) = qw0[j];
        *(int4*)(wbn + 1 * 8192 + sw) = qw1[j];
        *(int4*)(wbn + 2 * 8192 + sw) = qw2[j];
      }
      if (t < 144) *(f4*)(vbuf + (cur ^ 1) * 576 + t * 4) = qv;
      cur ^= 1;
    }
    __syncthreads();
  }

  // ---- store out ----
  #pragma unroll
  for (int nt = 0; nt < 4; ++nt) {
    #pragma unroll
    for (int rg = 0; rg < 4; ++rg) {
      const int row = r0 + wid * 16 + 4 * lg + rg;
      out[(size_t)row * U_DIM + lr + 16 * nt] = acc[nt][rg];
    }
  }
}

// =====================================================================
extern "C" void kernel_launch(void* const* d_in, const int* in_sizes, int n_in,
                              void* d_out, int out_size, void* d_ws, size_t ws_size,
                              hipStream_t stream)
{
  (void)in_sizes; (void)n_in; (void)out_size; (void)ws_size;
  const float* x    = (const float*)d_in[0];
  const float* W1   = (const float*)d_in[1];
  const float* b1   = (const float*)d_in[2];
  const float* W2   = (const float*)d_in[3];
  const float* b2   = (const float*)d_in[4];
  const float* Wg1  = (const float*)d_in[5];
  const float* bg1  = (const float*)d_in[6];
  const float* Wg2  = (const float*)d_in[7];
  const float* bg2  = (const float*)d_in[8];
  const float* Wp   = (const float*)d_in[9];
  const float* bp   = (const float*)d_in[10];
  const float* gm   = (const float*)d_in[11];
  const float* bt   = (const float*)d_in[12];
  const float* w1w  = (const float*)d_in[13];
  const float* b1w  = (const float*)d_in[14];
  const float* w2w  = (const float*)d_in[15];
  const float* b2w  = (const float*)d_in[16];
  const float* wg1w = (const float*)d_in[17];
  const float* bg1w = (const float*)d_in[18];
  const float* wg2w = (const float*)d_in[19];
  const float* bg2w = (const float*)d_in[20];
  const float* gmw  = (const float*)d_in[21];
  const float* btw  = (const float*)d_in[22];

  unsigned short* wtg = (unsigned short*)d_ws;             // 786432 B
  float* vect = (float*)((char*)d_ws + 786432);            // 73728 B

  float* out  = (float*)d_out;
  float* wout = out + (size_t)N_ROWS * U_DIM;

  vsn_prep<<<97, 256, 0, stream>>>(W2, Wg1, Wg2, W1, b1, b2, bg1, bg2, Wp, bp, gm, bt, wtg, vect);
  vsn_main<<<NBLK, NTHR, 0, stream>>>(x, wtg, vect, w1w, w2w, wg1w, wg2w,
                                      b1w, b2w, bg1w, bg2w, gmw, btw, out, wout);
}

// Round 4
// 207.272 us; speedup vs baseline: 1.0953x; 1.0953x over previous
//
#include <hip/hip_runtime.h>
#include <hip/hip_bf16.h>

// VariableSelectionNetwork (TFT VSN) fused kernel for MI355X / gfx950.
// B=64 T=512 F=32 U=64, rows N = B*T = 32768.
// out = concat( out[N][64], w[N][32] ) in f32.
//
// R3: barrier-free phase B. Weights read directly from L2 as pre-fragmented
// coalesced 16B chunks (no LDS staging, no per-f barrier). RPB=32, 4 waves:
// waves {0,1} handle f=0..15, waves {2,3} f=16..31 (same rows), combine at
// end via LDS. 1024 blocks -> 4 blocks/CU = 16 waves/CU. LDS 33792 B.

typedef float f4      __attribute__((ext_vector_type(4)));
typedef float f32x4   __attribute__((ext_vector_type(4)));
typedef short bf16x8  __attribute__((ext_vector_type(8)));
typedef unsigned short u16x4 __attribute__((ext_vector_type(4)));
typedef unsigned short u16x8 __attribute__((ext_vector_type(8)));

#define N_ROWS 32768
#define F_DIM  32
#define U_DIM  64
#define RPB    32           // rows per block
#define NTHR   256          // 4 waves
#define NBLK   (N_ROWS / RPB)   // 1024

// ---- LDS byte offsets (total 33792 B; 4 blocks/CU = 135168 <= 163840) ----
#define X_OFF   0           // f32 [32][36]  x tile                     (4608)
#define WT_OFF  4608        // u16 [32][40]  softmax weights (bf16)     (2560)
#define R1_OFF  7168        // phase A: wAl f32[4][1024] (16384) + vAl f32[192] (768)
                            // phase B: vstage f32[4][576] (9216) + cmb f4[512] (8192)
#define H2_OFF  24576       // u16 [4][16][72] h2 scratch (9216); phase-A hex f32[32][36]
#define SMEM_BYTES 33792

__device__ __forceinline__ unsigned short bfu(float x) {
  union { __hip_bfloat16 h; unsigned short u; } c;
  c.h = __float2bfloat16(x);
  return c.u;
}
__device__ __forceinline__ float bf2f(unsigned short u) {
  union { float f; unsigned v; } c; c.v = ((unsigned)u) << 16; return c.f;
}

// =====================================================================
// prep: W2/Wg1/Wg2 -> bf16 MFMA B-fragment-major layout in ws:
//   wtg[(m*32+f)*4096 + c*8 + j], c = nt*128 + kt*64 + lane,
//   value = W_m[f][u0+j][v],  v = (lane&15)+16*nt, u0 = 8*(lane>>4)+32*kt
// so a wave's B-fragment load for (m,f,nt,kt) is one coalesced 1KB read.
// Also pack 9 per-f vectors: vect[f][a][64].
// =====================================================================
__global__ __launch_bounds__(256) void vsn_prep(
    const float* __restrict__ W2,  const float* __restrict__ Wg1, const float* __restrict__ Wg2,
    const float* __restrict__ W1,  const float* __restrict__ b1,  const float* __restrict__ b2,
    const float* __restrict__ bg1, const float* __restrict__ bg2,
    const float* __restrict__ Wp,  const float* __restrict__ bp,
    const float* __restrict__ gamma_, const float* __restrict__ beta_,
    unsigned short* __restrict__ wtg, float* __restrict__ vect)
{
  const int t = threadIdx.x, blk = blockIdx.x;
  if (blk < 96) {
    const int m = blk >> 5, f = blk & 31;
    const float* src = (m == 0) ? W2 : (m == 1) ? Wg1 : Wg2;
    src += f * 4096;
    unsigned short* dst = wtg + (size_t)(m * 32 + f) * 4096;
    #pragma unroll
    for (int cc = 0; cc < 2; ++cc) {
      const int c  = t + cc * 256;          // chunk 0..511
      const int nt = c >> 7;
      const int rr = c & 127;
      const int kt = rr >> 6;
      const int ln = rr & 63;
      const int lg = ln >> 4, lrr = ln & 15;
      const int v  = lrr + 16 * nt;
      const int u0 = 8 * lg + 32 * kt;
      u16x8 tmp;
      #pragma unroll
      for (int j = 0; j < 8; ++j) tmp[j] = bfu(src[(u0 + j) * 64 + v]);
      *(u16x8*)(dst + c * 8) = tmp;
    }
  } else {
    // vec table: [f][a][64], a: 0 W1,1 b1,2 b2,3 bg1,4 bg2,5 Wp,6 bp,7 gamma,8 beta
    #pragma unroll
    for (int a = 0; a < 9; ++a) {
      const float* s = (a==0)?W1:(a==1)?b1:(a==2)?b2:(a==3)?bg1:(a==4)?bg2:
                       (a==5)?Wp:(a==6)?bp:(a==7)?gamma_:beta_;
      for (int i = t; i < 2048; i += 256)
        vect[(i >> 6) * 576 + a * 64 + (i & 63)] = s[i];
    }
  }
}

// =====================================================================
// main fused kernel
// =====================================================================
__global__ __launch_bounds__(NTHR, 4) void vsn_main(
    const float* __restrict__ x,
    const unsigned short* __restrict__ wtg,   // fragment-major bf16 weights
    const float* __restrict__ vect,           // [32][9][64]
    const float* __restrict__ w1w, const float* __restrict__ w2w,
    const float* __restrict__ wg1w, const float* __restrict__ wg2w,
    const float* __restrict__ b1w, const float* __restrict__ b2w,
    const float* __restrict__ bg1w, const float* __restrict__ bg2w,
    const float* __restrict__ gammaw, const float* __restrict__ betaw,
    float* __restrict__ out, float* __restrict__ wout)
{
  __shared__ __align__(16) char smem[SMEM_BYTES];
  const int t  = threadIdx.x;
  const int r0 = blockIdx.x * RPB;

  float* xt  = (float*)(smem + X_OFF);                       // [32][36] f32
  unsigned short* wtlb = (unsigned short*)(smem + WT_OFF);   // [32][40] bf16
  float* vst = (float*)(smem + R1_OFF);                      // [4][576] f32 (phase B)
  f4*   cmb4 = (f4*)(smem + R1_OFF + 9216);                  // [512] f4   (phase B tail)
  unsigned short* h2b = (unsigned short*)(smem + H2_OFF);    // [4][16][72] bf16
  // phase-A overlays
  float* wAl = (float*)(smem + R1_OFF);                      // [4][32][32] f32
  float* vAl = (float*)(smem + R1_OFF + 16384);              // [6][32] f32
  float* hex = (float*)(smem + H2_OFF);                      // [32][36] f32

  const int wid  = t >> 6;            // wave 0..3
  const int lane = t & 63;
  const int lr   = lane & 15;
  const int lg   = lane >> 4;
  const int fbase = (wid >> 1) * 16;  // waves 0,1 -> f 0..15 ; waves 2,3 -> 16..31
  const int rbase = (wid & 1) * 16;   // waves 0,2 -> rows 0..15 ; 1,3 -> 16..31

  // ---- stage x tile (coalesced f32x4): 32 rows x 32 f ----
  {
    f4 v = ((const f4*)(x + (size_t)r0 * F_DIM))[t];
    *((f4*)(xt + (t >> 3) * 36 + ((t & 7) << 2))) = v;
  }

  // ---- prefetch first-f vect into regs (held through phase A) ----
  const f4* vect4 = (const f4*)vect;
  f4 rv0 = vect4[fbase * 144 + lane];
  f4 rv1 = vect4[fbase * 144 + 64 + lane];
  f4 rv2 = {};
  if (lane < 16) rv2 = vect4[fbase * 144 + 128 + lane];

  // ---- stage phase-A weights ----
  #pragma unroll
  for (int i = 0; i < 4; ++i) {
    int i4 = t + i * NTHR;                   // 0..1023
    int m = i4 >> 8, off = (i4 & 255) << 2;
    const float* src = (m == 0) ? w1w : (m == 1) ? w2w : (m == 2) ? wg1w : wg2w;
    *(f4*)(wAl + m * 1024 + off) = *((const f4*)(src + off));
  }
  if (t < 48) {
    int m = t >> 3, off = (t & 7) << 2;
    const float* src = (m==0)?b1w:(m==1)?b2w:(m==2)?bg1w:(m==3)?bg2w:(m==4)?gammaw:betaw;
    *(f4*)(vAl + m * 32 + off) = *((const f4*)(src + off));
  }
  __syncthreads();

  // ================= PHASE A : weights GRN + softmax =================
  {
    const int ar = t >> 3;        // row 0..31
    const int g0 = (t & 7) << 2;  // this thread's 4 output columns

    // stage 1: h1 = elu(x @ w1w + b1w)
    float hacc[4];
    #pragma unroll
    for (int j = 0; j < 4; ++j) hacc[j] = vAl[0 * 32 + g0 + j];
    #pragma unroll
    for (int ff = 0; ff < 32; ++ff) {
      float xv = xt[ar * 36 + ff];
      f4 w0 = *(const f4*)(wAl + 0 * 1024 + ff * 32 + g0);
      #pragma unroll
      for (int j = 0; j < 4; ++j) hacc[j] += xv * w0[j];
    }
    #pragma unroll
    for (int j = 0; j < 4; ++j) { float z = hacc[j]; hacc[j] = z > 0.f ? z : (__expf(z) - 1.f); }
    *(f4*)(hex + ar * 36 + g0) = (f4){hacc[0], hacc[1], hacc[2], hacc[3]};
    __syncthreads();

    // stage 2: h2 = h1 @ w2w + b2w
    float h2acc[4];
    #pragma unroll
    for (int j = 0; j < 4; ++j) h2acc[j] = vAl[1 * 32 + g0 + j];
    #pragma unroll
    for (int ff = 0; ff < 32; ++ff) {
      float hv = hex[ar * 36 + ff];
      f4 w0 = *(const f4*)(wAl + 1 * 1024 + ff * 32 + g0);
      #pragma unroll
      for (int j = 0; j < 4; ++j) h2acc[j] += hv * w0[j];
    }
    __syncthreads();   // everyone done reading h1 from hex
    *(f4*)(hex + ar * 36 + g0) = (f4){h2acc[0], h2acc[1], h2acc[2], h2acc[3]};
    __syncthreads();

    // stage 3: GLU
    float aacc[4], bacc[4];
    #pragma unroll
    for (int j = 0; j < 4; ++j) { aacc[j] = vAl[2 * 32 + g0 + j]; bacc[j] = vAl[3 * 32 + g0 + j]; }
    #pragma unroll
    for (int ff = 0; ff < 32; ++ff) {
      float hv = hex[ar * 36 + ff];
      f4 wa0 = *(const f4*)(wAl + 2 * 1024 + ff * 32 + g0);
      f4 wb0 = *(const f4*)(wAl + 3 * 1024 + ff * 32 + g0);
      #pragma unroll
      for (int j = 0; j < 4; ++j) { aacc[j] += hv * wa0[j]; bacc[j] += hv * wb0[j]; }
    }
    float zz[4];
    #pragma unroll
    for (int j = 0; j < 4; ++j) {
      float sg = __builtin_amdgcn_rcpf(1.f + __expf(-bacc[j]));
      zz[j] = aacc[j] * sg + xt[ar * 36 + g0 + j];    // GLU + residual
    }
    __syncthreads();   // done reading h2 from hex
    *(f4*)(hex + ar * 36 + g0) = (f4){zz[0], zz[1], zz[2], zz[3]};
    __syncthreads();

    // LN + softmax over F=32 (each thread redundantly reduces its row)
    float s1 = 0.f, s2 = 0.f;
    #pragma unroll
    for (int ff = 0; ff < 32; ++ff) { float z = hex[ar * 36 + ff]; s1 += z; s2 += z * z; }
    float mA = s1 * 0.03125f;
    float vA = s2 * 0.03125f - mA * mA;
    float rsA = __builtin_amdgcn_rsqf(vA + 1e-3f);
    float mx = -1e30f;
    #pragma unroll
    for (int ff = 0; ff < 32; ++ff) {
      float y = (hex[ar * 36 + ff] - mA) * rsA * vAl[4 * 32 + ff] + vAl[5 * 32 + ff];
      mx = fmaxf(mx, y);
    }
    float es = 0.f;
    #pragma unroll
    for (int ff = 0; ff < 32; ++ff) {
      float y = (hex[ar * 36 + ff] - mA) * rsA * vAl[4 * 32 + ff] + vAl[5 * 32 + ff];
      es += __expf(y - mx);
    }
    float inv = __builtin_amdgcn_rcpf(es);
    float wv4[4];
    u16x4 wu;
    #pragma unroll
    for (int j = 0; j < 4; ++j) {
      float y = (hex[ar * 36 + g0 + j] - mA) * rsA * vAl[4 * 32 + g0 + j] + vAl[5 * 32 + g0 + j];
      wv4[j] = __expf(y - mx) * inv;
      wu[j] = bfu(wv4[j]);
    }
    *(u16x4*)(wtlb + ar * 40 + g0) = wu;   // bf16 copy for phase B
    *(f4*)(wout + (size_t)(r0 + ar) * 32 + g0) = (f4){wv4[0], wv4[1], wv4[2], wv4[3]};
    __syncthreads();   // phase A done; wAl/vAl/hex regions are now free
  }

  // ================= PHASE B : per-feature GRNs (MFMA, barrier-free) =====
  f4* vst4 = ((f4*)vst) + wid * 144;    // wave-private vect slot (576 f32)
  float* vsc = vst + wid * 576;
  unsigned short* h2w = h2b + wid * (16 * 72);   // wave-private [16][72] bf16

  // write first-f vect (wave-private; in-order DS, no barrier)
  vst4[lane] = rv0; vst4[64 + lane] = rv1;
  if (lane < 16) vst4[128 + lane] = rv2;

  const bf16x8* wf = (const bf16x8*)wtg;   // 512 fragments per (m,f)

  f32x4 acc[4];
  #pragma unroll
  for (int nt = 0; nt < 4; ++nt) acc[nt] = (f32x4){0.f, 0.f, 0.f, 0.f};

  for (int i = 0; i < 16; ++i) {
    const int f = fbase + i;

    // ---- GEMM1 B-fragment loads (8 coalesced 16B from L2) ----
    const int base0 = (0 * 32 + f) * 512 + lane;
    bf16x8 bfr[8];
    #pragma unroll
    for (int nt = 0; nt < 4; ++nt)
      #pragma unroll
      for (int kt = 0; kt < 2; ++kt)
        bfr[nt * 2 + kt] = wf[base0 + nt * 128 + kt * 64];

    // ---- h1 A-fragments, built in registers (rank-1 + ELU) ----
    const float s_ = xt[(rbase + lr) * 36 + f];
    bf16x8 afr[2];
    #pragma unroll
    for (int kt = 0; kt < 2; ++kt) {
      const int u0 = 8 * lg + 32 * kt;
      f4 wa  = *(const f4*)(vsc + u0);
      f4 wb_ = *(const f4*)(vsc + u0 + 4);
      f4 ba  = *(const f4*)(vsc + 64 + u0);
      f4 bb_ = *(const f4*)(vsc + 64 + u0 + 4);
      bf16x8 af;
      #pragma unroll
      for (int j = 0; j < 4; ++j) {
        float h = s_ * wa[j] + ba[j];
        h = h > 0.f ? h : (__expf(h) - 1.f);
        af[j] = (short)bfu(h);
      }
      #pragma unroll
      for (int j = 0; j < 4; ++j) {
        float h = s_ * wb_[j] + bb_[j];
        h = h > 0.f ? h : (__expf(h) - 1.f);
        af[4 + j] = (short)bfu(h);
      }
      afr[kt] = af;
    }

    // ---- GEMM1: h2 = h1 @ W2 ----
    f32x4 c1[4];
    #pragma unroll
    for (int nt = 0; nt < 4; ++nt) {
      c1[nt] = (f32x4){0.f, 0.f, 0.f, 0.f};
      #pragma unroll
      for (int kt = 0; kt < 2; ++kt)
        c1[nt] = __builtin_amdgcn_mfma_f32_16x16x32_bf16(afr[kt], bfr[nt * 2 + kt], c1[nt], 0, 0, 0);
    }

    // ---- h2 (+b2) -> wave-private LDS as bf16 ----
    #pragma unroll
    for (int nt = 0; nt < 4; ++nt) {
      const float b2v = vsc[2 * 64 + lr + 16 * nt];
      #pragma unroll
      for (int rg = 0; rg < 4; ++rg)
        h2w[(4 * lg + rg) * 72 + lr + 16 * nt] = bfu(c1[nt][rg] + b2v);
    }

    // ---- GEMM2a B loads (overlap the LDS drain) ----
    const int base1 = (1 * 32 + f) * 512 + lane;
    bf16x8 bfa[8];
    #pragma unroll
    for (int nt = 0; nt < 4; ++nt)
      #pragma unroll
      for (int kt = 0; kt < 2; ++kt)
        bfa[nt * 2 + kt] = wf[base1 + nt * 128 + kt * 64];

    asm volatile("s_waitcnt lgkmcnt(0)" ::: "memory");
    __builtin_amdgcn_sched_barrier(0);

    // ---- A2 fragments read directly as bf16 ----
    bf16x8 a2[2];
    #pragma unroll
    for (int kt = 0; kt < 2; ++kt)
      a2[kt] = *(const bf16x8*)(h2w + lr * 72 + 8 * lg + 32 * kt);

    // ---- GEMM2a ----
    f32x4 ca[4], cb[4];
    #pragma unroll
    for (int nt = 0; nt < 4; ++nt) {
      ca[nt] = (f32x4){0.f,0.f,0.f,0.f};
      #pragma unroll
      for (int kt = 0; kt < 2; ++kt)
        ca[nt] = __builtin_amdgcn_mfma_f32_16x16x32_bf16(a2[kt], bfa[nt * 2 + kt], ca[nt], 0, 0, 0);
    }

    // ---- GEMM2b loads + MFMA ----
    const int base2 = (2 * 32 + f) * 512 + lane;
    bf16x8 bfb[8];
    #pragma unroll
    for (int nt = 0; nt < 4; ++nt)
      #pragma unroll
      for (int kt = 0; kt < 2; ++kt)
        bfb[nt * 2 + kt] = wf[base2 + nt * 128 + kt * 64];
    #pragma unroll
    for (int nt = 0; nt < 4; ++nt) {
      cb[nt] = (f32x4){0.f,0.f,0.f,0.f};
      #pragma unroll
      for (int kt = 0; kt < 2; ++kt)
        cb[nt] = __builtin_amdgcn_mfma_f32_16x16x32_bf16(a2[kt], bfb[nt * 2 + kt], cb[nt], 0, 0, 0);
    }

    // ---- prefetch vect for f+1 into regs ----
    if (i < 15) {
      rv0 = vect4[(f + 1) * 144 + lane];
      rv1 = vect4[(f + 1) * 144 + 64 + lane];
      if (lane < 16) rv2 = vect4[(f + 1) * 144 + 128 + lane];
    }

    // ---- epilogue: GLU + residual + LN + weighted accumulate ----
    float xr[4], wr[4];
    #pragma unroll
    for (int rg = 0; rg < 4; ++rg) {
      const int rl = rbase + 4 * lg + rg;
      xr[rg] = xt[rl * 36 + f];
      wr[rg] = bf2f(wtlb[rl * 40 + f]);
    }
    float zf[4][4];
    float s1[4] = {0.f,0.f,0.f,0.f}, s2[4] = {0.f,0.f,0.f,0.f};
    #pragma unroll
    for (int nt = 0; nt < 4; ++nt) {
      const int u = lr + 16 * nt;
      const float bg1v = vsc[3 * 64 + u], bg2v = vsc[4 * 64 + u];
      const float wpv  = vsc[5 * 64 + u], bpv  = vsc[6 * 64 + u];
      #pragma unroll
      for (int rg = 0; rg < 4; ++rg) {
        float a = ca[nt][rg] + bg1v;
        float b = cb[nt][rg] + bg2v;
        float sg = __builtin_amdgcn_rcpf(1.f + __expf(-b));
        float z = a * sg + (xr[rg] * wpv + bpv);
        zf[nt][rg] = z;
        s1[rg] += z;
        s2[rg] += z * z;
      }
    }
    #pragma unroll
    for (int rg = 0; rg < 4; ++rg) {
      #pragma unroll
      for (int m = 1; m < 16; m <<= 1) {
        s1[rg] += __shfl_xor(s1[rg], m, 64);
        s2[rg] += __shfl_xor(s2[rg], m, 64);
      }
    }
    float mn[4], rs[4];
    #pragma unroll
    for (int rg = 0; rg < 4; ++rg) {
      mn[rg] = s1[rg] * 0.015625f;
      float var = s2[rg] * 0.015625f - mn[rg] * mn[rg];
      rs[rg] = __builtin_amdgcn_rsqf(var + 1e-3f);
    }
    #pragma unroll
    for (int nt = 0; nt < 4; ++nt) {
      const int u = lr + 16 * nt;
      const float gav = vsc[7 * 64 + u], bev = vsc[8 * 64 + u];
      #pragma unroll
      for (int rg = 0; rg < 4; ++rg) {
        float y = (zf[nt][rg] - mn[rg]) * rs[rg] * gav + bev;
        acc[nt][rg] += y * wr[rg];
      }
    }

    // ---- write f+1 vect to wave-private LDS (in-order DS; reads for f done) ----
    if (i < 15) {
      vst4[lane] = rv0; vst4[64 + lane] = rv1;
      if (lane < 16) vst4[128 + lane] = rv2;
    }
  }

  // ---- combine feature-halves and store ----
  if (wid >= 2) {
    #pragma unroll
    for (int nt = 0; nt < 4; ++nt)
      cmb4[(wid - 2) * 256 + nt * 64 + lane] = acc[nt];
  }
  __syncthreads();
  if (wid < 2) {
    #pragma unroll
    for (int nt = 0; nt < 4; ++nt) {
      f4 o = acc[nt] + cmb4[wid * 256 + nt * 64 + lane];
      #pragma unroll
      for (int rg = 0; rg < 4; ++rg) {
        const int row = r0 + rbase + 4 * lg + rg;
        out[(size_t)row * U_DIM + lr + 16 * nt] = o[rg];
      }
    }
  }
}

// =====================================================================
extern "C" void kernel_launch(void* const* d_in, const int* in_sizes, int n_in,
                              void* d_out, int out_size, void* d_ws, size_t ws_size,
                              hipStream_t stream)
{
  (void)in_sizes; (void)n_in; (void)out_size; (void)ws_size;
  const float* x    = (const float*)d_in[0];
  const float* W1   = (const float*)d_in[1];
  const float* b1   = (const float*)d_in[2];
  const float* W2   = (const float*)d_in[3];
  const float* b2   = (const float*)d_in[4];
  const float* Wg1  = (const float*)d_in[5];
  const float* bg1  = (const float*)d_in[6];
  const float* Wg2  = (const float*)d_in[7];
  const float* bg2  = (const float*)d_in[8];
  const float* Wp   = (const float*)d_in[9];
  const float* bp   = (const float*)d_in[10];
  const float* gm   = (const float*)d_in[11];
  const float* bt   = (const float*)d_in[12];
  const float* w1w  = (const float*)d_in[13];
  const float* b1w  = (const float*)d_in[14];
  const float* w2w  = (const float*)d_in[15];
  const float* b2w  = (const float*)d_in[16];
  const float* wg1w = (const float*)d_in[17];
  const float* bg1w = (const float*)d_in[18];
  const float* wg2w = (const float*)d_in[19];
  const float* bg2w = (const float*)d_in[20];
  const float* gmw  = (const float*)d_in[21];
  const float* btw  = (const float*)d_in[22];

  unsigned short* wtg = (unsigned short*)d_ws;             // 786432 B
  float* vect = (float*)((char*)d_ws + 786432);            // 73728 B

  float* out  = (float*)d_out;
  float* wout = out + (size_t)N_ROWS * U_DIM;

  vsn_prep<<<97, 256, 0, stream>>>(W2, Wg1, Wg2, W1, b1, b2, bg1, bg2, Wp, bp, gm, bt, wtg, vect);
  vsn_main<<<NBLK, NTHR, 0, stream>>>(x, wtg, vect, w1w, w2w, wg1w, wg2w,
                                      b1w, b2w, bg1w, bg2w, gmw, btw, out, wout);
}